// Round 1
// baseline (431.073 us; speedup 1.0000x reference)
//
#include <hip/hip_runtime.h>
#include <cstdint>
#include <cstddef>

// ---------------- problem constants ----------------
#define D_MODEL 1024
#define SEQ_L   4096
#define BATCH   4
#define NROWS   (BATCH*SEQ_L)     // 16384
#define DSTATE  16
#define DTRANK  64
#define NDBL    96                // DTRANK + 2*DSTATE
#define NCHUNK  32                // scan chunks
#define CLEN    128               // L / NCHUNK

typedef __attribute__((ext_vector_type(8))) short bf16x8;
typedef __attribute__((ext_vector_type(4))) float f32x4;

__device__ __forceinline__ unsigned short f2bf(float f) {
  union { float f; unsigned u; } v; v.f = f;
  unsigned u = v.u;
  unsigned r = u + 0x7FFFu + ((u >> 16) & 1u);   // RNE
  return (unsigned short)(r >> 16);
}

__device__ __forceinline__ float silu(float v) {
  return v / (1.f + __expf(-v));
}

// ---------------- 1. LayerNorm -> bf16 ----------------
__global__ __launch_bounds__(256) void ln_kernel(const float* __restrict__ f,
                                                 const float* __restrict__ g,
                                                 const float* __restrict__ bta,
                                                 unsigned short* __restrict__ fnb) {
  int row = blockIdx.x;
  int tid = threadIdx.x;
  const float* fr = f + (size_t)row * D_MODEL;
  float4 v = *(const float4*)&fr[tid * 4];
  float s  = v.x + v.y + v.z + v.w;
  float ss = v.x*v.x + v.y*v.y + v.z*v.z + v.w*v.w;
  #pragma unroll
  for (int o = 32; o > 0; o >>= 1) { s += __shfl_down(s, o); ss += __shfl_down(ss, o); }
  __shared__ float rs[8];
  int lane = tid & 63, w = tid >> 6;
  if (lane == 0) { rs[w] = s; rs[4 + w] = ss; }
  __syncthreads();
  if (tid == 0) {
    float S = rs[0] + rs[1] + rs[2] + rs[3];
    float SS = rs[4] + rs[5] + rs[6] + rs[7];
    float mu = S * (1.f / D_MODEL);
    float var = SS * (1.f / D_MODEL) - mu * mu;
    rs[0] = mu; rs[1] = rsqrtf(var + 1e-5f);
  }
  __syncthreads();
  float mu = rs[0], rstd = rs[1];
  float4 gv = *(const float4*)&g[tid * 4];
  float4 bv = *(const float4*)&bta[tid * 4];
  ushort4 o;
  o.x = f2bf((v.x - mu) * rstd * gv.x + bv.x);
  o.y = f2bf((v.y - mu) * rstd * gv.y + bv.y);
  o.z = f2bf((v.z - mu) * rstd * gv.z + bv.z);
  o.w = f2bf((v.w - mu) * rstd * gv.w + bv.w);
  *(ushort4*)&fnb[(size_t)row * D_MODEL + tid * 4] = o;
}

// ---------------- 2. Wx -> bf16, transposed [n][k] ----------------
__global__ __launch_bounds__(256) void cast_transpose(const float* __restrict__ W,
                                                      unsigned short* __restrict__ Wt) {
  __shared__ float tile[32][33];
  int tx = threadIdx.x & 31, ty = threadIdx.x >> 5;  // ty 0..7
  int n0 = blockIdx.x * 32, k0 = blockIdx.y * 32;
  #pragma unroll
  for (int i = 0; i < 4; ++i) {
    int k = ty + i * 8;
    tile[k][tx] = W[(size_t)(k0 + k) * D_MODEL + n0 + tx];
  }
  __syncthreads();
  #pragma unroll
  for (int i = 0; i < 4; ++i) {
    int n = ty + i * 8;
    Wt[(size_t)(n0 + n) * D_MODEL + k0 + tx] = f2bf(tile[tx][n]);
  }
}

// ---------------- 3. GEMM1: x_lin = fn @ Wx + bx  (bf16 MFMA) ----------------
// 128x128 tile, BK=32, 4 waves, each wave 64x64 (4x4 fragments of 16x16x32)
__global__ __launch_bounds__(256) void gemm1(const unsigned short* __restrict__ Ab,
                                             const unsigned short* __restrict__ Bt,
                                             const float* __restrict__ bias,
                                             float* __restrict__ C) {
  __shared__ __align__(16) unsigned short As[128 * 32];  // [m][k]
  __shared__ __align__(16) unsigned short Bs[128 * 32];  // [n][k]
  const int K = D_MODEL, N = D_MODEL;
  int tid = threadIdx.x;
  int row0 = blockIdx.x * 128;
  int col0 = blockIdx.y * 128;
  int wave = tid >> 6, lane = tid & 63;
  int wr = wave >> 1, wc = wave & 1;
  int lr = lane & 15, half = lane >> 4;
  f32x4 acc[4][4] = {};
  int c0 = tid, c1 = tid + 256;            // 16B chunks (8 bf16)
  int ar0 = c0 >> 2, ak0 = (c0 & 3) * 8;
  int ar1 = c1 >> 2, ak1 = (c1 & 3) * 8;
  for (int k0 = 0; k0 < K; k0 += 32) {
    __syncthreads();
    *(uint4*)&As[ar0 * 32 + ak0] = *(const uint4*)&Ab[(size_t)(row0 + ar0) * K + k0 + ak0];
    *(uint4*)&As[ar1 * 32 + ak1] = *(const uint4*)&Ab[(size_t)(row0 + ar1) * K + k0 + ak1];
    *(uint4*)&Bs[ar0 * 32 + ak0] = *(const uint4*)&Bt[(size_t)(col0 + ar0) * K + k0 + ak0];
    *(uint4*)&Bs[ar1 * 32 + ak1] = *(const uint4*)&Bt[(size_t)(col0 + ar1) * K + k0 + ak1];
    __syncthreads();
    bf16x8 a[4], b[4];
    #pragma unroll
    for (int m = 0; m < 4; ++m) a[m] = *(const bf16x8*)&As[(wr * 64 + m * 16 + lr) * 32 + half * 8];
    #pragma unroll
    for (int n = 0; n < 4; ++n) b[n] = *(const bf16x8*)&Bs[(wc * 64 + n * 16 + lr) * 32 + half * 8];
    #pragma unroll
    for (int m = 0; m < 4; ++m)
      #pragma unroll
      for (int n = 0; n < 4; ++n)
        acc[m][n] = __builtin_amdgcn_mfma_f32_16x16x32_bf16(a[m], b[n], acc[m][n], 0, 0, 0);
  }
  // C/D layout: col = lane&15, row = (lane>>4)*4 + reg   [verified m89/m91]
  #pragma unroll
  for (int m = 0; m < 4; ++m) {
    int grb = row0 + wr * 64 + m * 16 + half * 4;
    #pragma unroll
    for (int n = 0; n < 4; ++n) {
      int gc = col0 + wc * 64 + n * 16 + lr;
      float bv = bias[gc];
      #pragma unroll
      for (int r = 0; r < 4; ++r)
        C[(size_t)(grb + r) * N + gc] = acc[m][n][r] + bv;
    }
  }
}

// ---------------- 4. causal depthwise conv (K=4) + bias + SiLU ----------------
__global__ __launch_bounds__(256) void conv_silu(const float* __restrict__ xlin,
                                                 const float* __restrict__ cw,
                                                 const float* __restrict__ cb,
                                                 float* __restrict__ xo) {
  int idx = blockIdx.x * 256 + threadIdx.x;   // one float4 along D
  int d4 = idx & 255;
  int rowflat = idx >> 8;                     // b*L + l
  int l = rowflat & (SEQ_L - 1);
  int d = d4 * 4;
  float4 cbv = *(const float4*)&cb[d];
  float a0 = cbv.x, a1 = cbv.y, a2 = cbv.z, a3 = cbv.w;
  float w[4][4];
  #pragma unroll
  for (int j = 0; j < 4; ++j) {
    float4 t = *(const float4*)&cw[(d + j) * 4];
    w[j][0] = t.x; w[j][1] = t.y; w[j][2] = t.z; w[j][3] = t.w;
  }
  #pragma unroll
  for (int k = 0; k < 4; ++k) {
    int ls = l - 3 + k;
    if (ls >= 0) {
      float4 v = *(const float4*)&xlin[(size_t)(rowflat - 3 + k) * D_MODEL + d];
      a0 += v.x * w[0][k]; a1 += v.y * w[1][k]; a2 += v.z * w[2][k]; a3 += v.w * w[3][k];
    }
  }
  float4 o; o.x = silu(a0); o.y = silu(a1); o.z = silu(a2); o.w = silu(a3);
  *(float4*)&xo[(size_t)rowflat * D_MODEL + d] = o;
}

// ---------------- 5. GEMM2: x_dbl = x @ Wxp  (16384x1024 @ 1024x96) ----------------
__global__ __launch_bounds__(256) void gemm2(const float* __restrict__ X,
                                             const float* __restrict__ W,
                                             float* __restrict__ Y) {
  __shared__ __align__(16) float xs[64][36];
  __shared__ __align__(16) float wsh[32][100];
  int tid = threadIdx.x;
  int row0 = blockIdx.x * 64;
  int tr = tid >> 4, tc = tid & 15;
  float acc[4][6] = {};
  for (int k0 = 0; k0 < D_MODEL; k0 += 32) {
    __syncthreads();
    #pragma unroll
    for (int i = 0; i < 2; ++i) {
      int cc = tid + i * 256; int r = cc >> 3, ko = (cc & 7) * 4;
      *(float4*)&xs[r][ko] = *(const float4*)&X[(size_t)(row0 + r) * D_MODEL + k0 + ko];
    }
    #pragma unroll
    for (int i = 0; i < 3; ++i) {
      int cc = tid + i * 256; int r = cc / 24, no = (cc % 24) * 4;
      *(float4*)&wsh[r][no] = *(const float4*)&W[(size_t)(k0 + r) * NDBL + no];
    }
    __syncthreads();
    #pragma unroll
    for (int k = 0; k < 32; ++k) {
      float a[4], bb[6];
      #pragma unroll
      for (int i = 0; i < 4; ++i) a[i] = xs[tr * 4 + i][k];
      #pragma unroll
      for (int j = 0; j < 6; ++j) bb[j] = wsh[k][tc * 6 + j];
      #pragma unroll
      for (int i = 0; i < 4; ++i)
        #pragma unroll
        for (int j = 0; j < 6; ++j) acc[i][j] += a[i] * bb[j];
    }
  }
  #pragma unroll
  for (int i = 0; i < 4; ++i)
    #pragma unroll
    for (int j = 0; j < 6; ++j)
      Y[(size_t)(row0 + tr * 4 + i) * NDBL + tc * 6 + j] = acc[i][j];
}

// ---------------- 6. GEMM3: delta = softplus(dt @ Wdt + bdt) ----------------
__global__ __launch_bounds__(256) void gemm3(const float* __restrict__ XD,
                                             const float* __restrict__ Wdt,
                                             const float* __restrict__ bdt,
                                             float* __restrict__ Dl) {
  __shared__ __align__(16) float as_[64][68];
  __shared__ __align__(16) float bs_[64][68];
  int tid = threadIdx.x;
  int row0 = blockIdx.x * 64;
  int col0 = blockIdx.y * 64;
  #pragma unroll
  for (int i = 0; i < 4; ++i) {
    int cc = tid + i * 256; int r = cc >> 4, ko = (cc & 15) * 4;
    *(float4*)&as_[r][ko] = *(const float4*)&XD[(size_t)(row0 + r) * NDBL + ko];
    *(float4*)&bs_[r][ko] = *(const float4*)&Wdt[(size_t)r * D_MODEL + col0 + ko];
  }
  __syncthreads();
  int tr = tid >> 4, tc = tid & 15;
  float acc[4][4] = {};
  #pragma unroll 8
  for (int k = 0; k < 64; ++k) {
    float a[4], bb[4];
    #pragma unroll
    for (int i = 0; i < 4; ++i) a[i] = as_[tr * 4 + i][k];
    #pragma unroll
    for (int j = 0; j < 4; ++j) bb[j] = bs_[k][tc * 4 + j];
    #pragma unroll
    for (int i = 0; i < 4; ++i)
      #pragma unroll
      for (int j = 0; j < 4; ++j) acc[i][j] += a[i] * bb[j];
  }
  #pragma unroll
  for (int i = 0; i < 4; ++i) {
    int gr = row0 + tr * 4 + i;
    #pragma unroll
    for (int j = 0; j < 4; ++j) {
      int gc = col0 + tc * 4 + j;
      float z = acc[i][j] + bdt[gc];
      float sp = (z > 20.f) ? z : log1pf(__expf(z));
      Dl[(size_t)gr * D_MODEL + gc] = sp;
    }
  }
}

// ---------------- 7-9. chunked linear-recurrence scan ----------------
// h_t = (delta*A) h_{t-1} + (delta*x) B_t ;  y = <h, C_t> ; out = y + x*Dp
__global__ __launch_bounds__(256) void scan_a(const float* __restrict__ delta,
                                              const float* __restrict__ x,
                                              const float* __restrict__ xdbl,
                                              const float* __restrict__ A_log,
                                              float* __restrict__ Pbuf,
                                              float* __restrict__ Hend) {
  int c = blockIdx.x, b = blockIdx.y, dq = blockIdx.z;
  int tid = threadIdx.x;
  int d = dq * 256 + tid;
  __shared__ __align__(16) float Bl[CLEN * 16];
  int rowbase = b * SEQ_L + c * CLEN;
  #pragma unroll
  for (int i = 0; i < 2; ++i) {
    int cc = tid + i * 256; int t = cc >> 2, no = (cc & 3) * 4;
    *(float4*)&Bl[t * 16 + no] = *(const float4*)&xdbl[(size_t)(rowbase + t) * NDBL + DTRANK + no];
  }
  __syncthreads();
  float Ar[16], h[16], P[16];
  #pragma unroll
  for (int n = 0; n < 16; ++n) { Ar[n] = -__expf(A_log[d * 16 + n]); h[n] = 0.f; P[n] = 1.f; }
  for (int t = 0; t < CLEN; ++t) {
    size_t roff = (size_t)(rowbase + t) * D_MODEL + d;
    float dlt = delta[roff];
    float xv = x[roff];
    float dx = dlt * xv;
    #pragma unroll
    for (int n = 0; n < 16; ++n) {
      float a = dlt * Ar[n];
      P[n] *= a;
      h[n] = a * h[n] + dx * Bl[t * 16 + n];
    }
  }
  size_t base = (size_t)c * (BATCH * D_MODEL * 16) + ((size_t)(b * D_MODEL + d)) * 16;
  #pragma unroll
  for (int n = 0; n < 16; n += 4) {
    *(float4*)&Pbuf[base + n] = make_float4(P[n], P[n+1], P[n+2], P[n+3]);
    *(float4*)&Hend[base + n] = make_float4(h[n], h[n+1], h[n+2], h[n+3]);
  }
}

__global__ __launch_bounds__(256) void scan_b(const float* __restrict__ P,
                                              const float* __restrict__ Hend,
                                              float* __restrict__ Hin) {
  int j = blockIdx.x * 256 + threadIdx.x;   // 65536 = B*D*16
  float H = 0.f;
  for (int c = 0; c < NCHUNK; ++c) {
    size_t off = (size_t)c * (BATCH * D_MODEL * 16) + j;
    Hin[off] = H;
    H = P[off] * H + Hend[off];
  }
}

__global__ __launch_bounds__(256) void scan_c(const float* __restrict__ delta,
                                              const float* __restrict__ x,
                                              const float* __restrict__ xdbl,
                                              const float* __restrict__ A_log,
                                              const float* __restrict__ Hin,
                                              const float* __restrict__ Dp,
                                              float* __restrict__ out) {
  int c = blockIdx.x, b = blockIdx.y, dq = blockIdx.z;
  int tid = threadIdx.x;
  int d = dq * 256 + tid;
  __shared__ __align__(16) float Bl[CLEN * 16];
  __shared__ __align__(16) float Cl[CLEN * 16];
  int rowbase = b * SEQ_L + c * CLEN;
  #pragma unroll
  for (int i = 0; i < 2; ++i) {
    int cc = tid + i * 256; int t = cc >> 2, no = (cc & 3) * 4;
    *(float4*)&Bl[t * 16 + no] = *(const float4*)&xdbl[(size_t)(rowbase + t) * NDBL + DTRANK + no];
    *(float4*)&Cl[t * 16 + no] = *(const float4*)&xdbl[(size_t)(rowbase + t) * NDBL + DTRANK + DSTATE + no];
  }
  __syncthreads();
  float Ar[16], h[16];
  size_t hbase = (size_t)c * (BATCH * D_MODEL * 16) + ((size_t)(b * D_MODEL + d)) * 16;
  #pragma unroll
  for (int n = 0; n < 16; n += 4) {
    float4 hv = *(const float4*)&Hin[hbase + n];
    h[n] = hv.x; h[n+1] = hv.y; h[n+2] = hv.z; h[n+3] = hv.w;
  }
  #pragma unroll
  for (int n = 0; n < 16; ++n) Ar[n] = -__expf(A_log[d * 16 + n]);
  float dpv = Dp[d];
  for (int t = 0; t < CLEN; ++t) {
    size_t roff = (size_t)(rowbase + t) * D_MODEL + d;
    float dlt = delta[roff];
    float xv = x[roff];
    float dx = dlt * xv;
    float y = 0.f;
    #pragma unroll
    for (int n = 0; n < 16; ++n) {
      float a = dlt * Ar[n];
      h[n] = a * h[n] + dx * Bl[t * 16 + n];
      y += h[n] * Cl[t * 16 + n];
    }
    out[roff] = y + xv * dpv;
  }
}

// ---------------- launch ----------------
extern "C" void kernel_launch(void* const* d_in, const int* in_sizes, int n_in,
                              void* d_out, int out_size, void* d_ws, size_t ws_size,
                              hipStream_t stream) {
  const float* f     = (const float*)d_in[0];
  const float* ln_g  = (const float*)d_in[1];
  const float* ln_b  = (const float*)d_in[2];
  const float* Wx    = (const float*)d_in[3];
  const float* bx    = (const float*)d_in[4];
  const float* convw = (const float*)d_in[5];
  const float* convb = (const float*)d_in[6];
  const float* Wxp   = (const float*)d_in[7];
  const float* Wdt   = (const float*)d_in[8];
  const float* bdt   = (const float*)d_in[9];
  const float* A_log = (const float*)d_in[10];
  const float* Dp    = (const float*)d_in[11];
  float* out = (float*)d_out;
  char* ws = (char*)d_ws;

  unsigned short* fnb = (unsigned short*)(ws);                 // 32 MiB bf16 LN output
  float* xlin  = (float*)(ws + 33554432);                      // 64 MiB (aliased as delta later)
  float* xbuf  = (float*)(ws + 100663296);                     // 64 MiB conv+silu output
  float* xdbl  = (float*)(ws + 167772160);                     // 6 MiB
  unsigned short* wxt = (unsigned short*)(ws + 174063616);     // 2 MiB Wx^T bf16
  float* Pbuf  = (float*)(ws + 176160768);                     // 8 MiB
  float* Hend  = (float*)(ws + 184549376);                     // 8 MiB
  float* Hin   = (float*)(ws + 192937984);                     // 8 MiB
  float* delta = xlin;                                         // xlin dead after conv

  ln_kernel<<<dim3(NROWS), dim3(256), 0, stream>>>(f, ln_g, ln_b, fnb);
  cast_transpose<<<dim3(32, 32), dim3(256), 0, stream>>>(Wx, wxt);
  gemm1<<<dim3(NROWS / 128, D_MODEL / 128), dim3(256), 0, stream>>>(fnb, wxt, bx, xlin);
  conv_silu<<<dim3(NROWS * (D_MODEL / 4) / 256), dim3(256), 0, stream>>>(xlin, convw, convb, xbuf);
  gemm2<<<dim3(NROWS / 64), dim3(256), 0, stream>>>(xbuf, Wxp, xdbl);
  gemm3<<<dim3(NROWS / 64, D_MODEL / 64), dim3(256), 0, stream>>>(xdbl, Wdt, bdt, delta);
  scan_a<<<dim3(NCHUNK, BATCH, 4), dim3(256), 0, stream>>>(delta, xbuf, xdbl, A_log, Pbuf, Hend);
  scan_b<<<dim3(256), dim3(256), 0, stream>>>(Pbuf, Hend, Hin);
  scan_c<<<dim3(NCHUNK, BATCH, 4), dim3(256), 0, stream>>>(delta, xbuf, xdbl, A_log, Hin, Dp, out);
}

// Round 2
// 391.679 us; speedup vs baseline: 1.1006x; 1.1006x over previous
//
#include <hip/hip_runtime.h>
#include <cstdint>
#include <cstddef>

// ---------------- problem constants ----------------
#define D_MODEL 1024
#define SEQ_L   4096
#define BATCH   4
#define NROWS   (BATCH*SEQ_L)     // 16384
#define DSTATE  16
#define DTRANK  64
#define NDBL    96                // DTRANK + 2*DSTATE
#define NCHUNK  32                // scan chunks
#define CLEN    128               // L / NCHUNK

typedef __attribute__((ext_vector_type(8))) short bf16x8;
typedef __attribute__((ext_vector_type(4))) float f32x4;

typedef __attribute__((address_space(1))) const unsigned int* as1_u32p;
typedef __attribute__((address_space(3))) unsigned int* as3_u32p;

__device__ __forceinline__ void gload16(const void* g, void* l) {
  // async global->LDS, 16B per lane; LDS dest must be wave-uniform base + lane*16
  __builtin_amdgcn_global_load_lds((as1_u32p)g, (as3_u32p)l, 16, 0, 0);
}

__device__ __forceinline__ unsigned short f2bf(float f) {
  union { float f; unsigned u; } v; v.f = f;
  unsigned u = v.u;
  unsigned r = u + 0x7FFFu + ((u >> 16) & 1u);   // RNE
  return (unsigned short)(r >> 16);
}

__device__ __forceinline__ float silu(float v) {
  return v / (1.f + __expf(-v));
}

// XOR swizzle for 64-elem bf16 rows (128B): spreads the 16-lane column read
// across 8 bank groups -> 2-way (free, m136). Mask multiples of 8 keep
// 4/8-elem chunks contiguous.
__device__ __forceinline__ int swz64(int r, int e) { return e ^ ((r & 7) << 3); }

// ---------------- 1. LayerNorm -> bf16 ----------------
__global__ __launch_bounds__(256) void ln_kernel(const float* __restrict__ f,
                                                 const float* __restrict__ g,
                                                 const float* __restrict__ bta,
                                                 unsigned short* __restrict__ fnb) {
  int row = blockIdx.x;
  int tid = threadIdx.x;
  const float* fr = f + (size_t)row * D_MODEL;
  float4 v = *(const float4*)&fr[tid * 4];
  float s  = v.x + v.y + v.z + v.w;
  float ss = v.x*v.x + v.y*v.y + v.z*v.z + v.w*v.w;
  #pragma unroll
  for (int o = 32; o > 0; o >>= 1) { s += __shfl_down(s, o); ss += __shfl_down(ss, o); }
  __shared__ float rs[8];
  int lane = tid & 63, w = tid >> 6;
  if (lane == 0) { rs[w] = s; rs[4 + w] = ss; }
  __syncthreads();
  if (tid == 0) {
    float S = rs[0] + rs[1] + rs[2] + rs[3];
    float SS = rs[4] + rs[5] + rs[6] + rs[7];
    float mu = S * (1.f / D_MODEL);
    float var = SS * (1.f / D_MODEL) - mu * mu;
    rs[0] = mu; rs[1] = rsqrtf(var + 1e-5f);
  }
  __syncthreads();
  float mu = rs[0], rstd = rs[1];
  float4 gv = *(const float4*)&g[tid * 4];
  float4 bv = *(const float4*)&bta[tid * 4];
  ushort4 o;
  o.x = f2bf((v.x - mu) * rstd * gv.x + bv.x);
  o.y = f2bf((v.y - mu) * rstd * gv.y + bv.y);
  o.z = f2bf((v.z - mu) * rstd * gv.z + bv.z);
  o.w = f2bf((v.w - mu) * rstd * gv.w + bv.w);
  *(ushort4*)&fnb[(size_t)row * D_MODEL + tid * 4] = o;
}

// ---------------- 2. generic transpose+cast: src [rows][cols] f32 -> dst [cols][rows] bf16
__global__ __launch_bounds__(256) void tcast(const float* __restrict__ W,
                                             unsigned short* __restrict__ Wt,
                                             int rows, int cols) {
  __shared__ float tile[32][33];
  int tx = threadIdx.x & 31, ty = threadIdx.x >> 5;  // ty 0..7
  int c0 = blockIdx.x * 32, r0 = blockIdx.y * 32;
  #pragma unroll
  for (int i = 0; i < 4; ++i) {
    int r = ty + i * 8;
    tile[r][tx] = W[(size_t)(r0 + r) * cols + c0 + tx];
  }
  __syncthreads();
  #pragma unroll
  for (int i = 0; i < 4; ++i) {
    int n = ty + i * 8;
    Wt[(size_t)(c0 + n) * rows + r0 + tx] = f2bf(tile[tx][n]);
  }
}

// ---------------- 3. GEMM1: x_lin = fn @ Wx + bx  (bf16 MFMA, gload_lds staging) ----------------
// 128x128 tile, BK=32, 4 waves, each wave 64x64 (4x4 fragments of 16x16x32)
__global__ __launch_bounds__(256) void gemm1(const unsigned short* __restrict__ Ab,
                                             const unsigned short* __restrict__ Bt,
                                             const float* __restrict__ bias,
                                             float* __restrict__ C) {
  __shared__ __align__(16) unsigned short As[128 * 32];  // [m][k], linear (gload_lds)
  __shared__ __align__(16) unsigned short Bs[128 * 32];  // [n][k]
  const int K = D_MODEL, N = D_MODEL;
  int tid = threadIdx.x;
  int row0 = blockIdx.x * 128;
  int col0 = blockIdx.y * 128;
  int wave = tid >> 6, lane = tid & 63;
  int wr = wave >> 1, wc = wave & 1;
  int lr = lane & 15, half = lane >> 4;
  f32x4 acc[4][4] = {};
  // chunk c (16B): LDS elem offset = (c>>2)*32 + (c&3)*8 = c*8  -> linear, gload_lds-compatible
  int c0 = tid, c1 = tid + 256;
  int ar0 = c0 >> 2, ak0 = (c0 & 3) * 8;
  int ar1 = c1 >> 2, ak1 = (c1 & 3) * 8;
  for (int k0 = 0; k0 < K; k0 += 32) {
    __syncthreads();
    gload16(&Ab[(size_t)(row0 + ar0) * K + k0 + ak0], &As[c0 * 8]);
    gload16(&Ab[(size_t)(row0 + ar1) * K + k0 + ak1], &As[c1 * 8]);
    gload16(&Bt[(size_t)(col0 + ar0) * K + k0 + ak0], &Bs[c0 * 8]);
    gload16(&Bt[(size_t)(col0 + ar1) * K + k0 + ak1], &Bs[c1 * 8]);
    __syncthreads();
    bf16x8 a[4], b[4];
    #pragma unroll
    for (int m = 0; m < 4; ++m) a[m] = *(const bf16x8*)&As[(wr * 64 + m * 16 + lr) * 32 + half * 8];
    #pragma unroll
    for (int n = 0; n < 4; ++n) b[n] = *(const bf16x8*)&Bs[(wc * 64 + n * 16 + lr) * 32 + half * 8];
    #pragma unroll
    for (int m = 0; m < 4; ++m)
      #pragma unroll
      for (int n = 0; n < 4; ++n)
        acc[m][n] = __builtin_amdgcn_mfma_f32_16x16x32_bf16(a[m], b[n], acc[m][n], 0, 0, 0);
  }
  // C/D layout: col = lane&15, row = (lane>>4)*4 + reg
  #pragma unroll
  for (int m = 0; m < 4; ++m) {
    int grb = row0 + wr * 64 + m * 16 + half * 4;
    #pragma unroll
    for (int n = 0; n < 4; ++n) {
      int gc = col0 + wc * 64 + n * 16 + lr;
      float bv = bias[gc];
      #pragma unroll
      for (int r = 0; r < 4; ++r)
        C[(size_t)(grb + r) * N + gc] = acc[m][n][r] + bv;
    }
  }
}

// ---------------- 4. causal depthwise conv (K=4) + bias + SiLU ----------------
__global__ __launch_bounds__(256) void conv_silu(const float* __restrict__ xlin,
                                                 const float* __restrict__ cw,
                                                 const float* __restrict__ cb,
                                                 float* __restrict__ xo) {
  int idx = blockIdx.x * 256 + threadIdx.x;   // one float4 along D
  int d4 = idx & 255;
  int rowflat = idx >> 8;                     // b*L + l
  int l = rowflat & (SEQ_L - 1);
  int d = d4 * 4;
  float4 cbv = *(const float4*)&cb[d];
  float a0 = cbv.x, a1 = cbv.y, a2 = cbv.z, a3 = cbv.w;
  float w[4][4];
  #pragma unroll
  for (int j = 0; j < 4; ++j) {
    float4 t = *(const float4*)&cw[(d + j) * 4];
    w[j][0] = t.x; w[j][1] = t.y; w[j][2] = t.z; w[j][3] = t.w;
  }
  #pragma unroll
  for (int k = 0; k < 4; ++k) {
    int ls = l - 3 + k;
    if (ls >= 0) {
      float4 v = *(const float4*)&xlin[(size_t)(rowflat - 3 + k) * D_MODEL + d];
      a0 += v.x * w[0][k]; a1 += v.y * w[1][k]; a2 += v.z * w[2][k]; a3 += v.w * w[3][k];
    }
  }
  float4 o; o.x = silu(a0); o.y = silu(a1); o.z = silu(a2); o.w = silu(a3);
  *(float4*)&xo[(size_t)rowflat * D_MODEL + d] = o;
}

// ---------------- 5. GEMM2 (MFMA): x_dbl = x @ Wxp  (16384x1024 @ 1024x96) ----------------
// tile M=64, N=96 (full), BK=64; 4 waves, wave w: rows w*16..w*16+15, 6 n-frags
__global__ __launch_bounds__(256) void gemm2(const float* __restrict__ X,
                                             const unsigned short* __restrict__ WT, // [96][1024] bf16
                                             float* __restrict__ Y) {
  __shared__ __align__(16) unsigned short As[64 * 64];   // [m][k] swizzled
  __shared__ __align__(16) unsigned short Bs[96 * 64];   // [n][k] swizzled
  int tid = threadIdx.x;
  int row0 = blockIdx.x * 64;
  int wave = tid >> 6, lane = tid & 63;
  int lr = lane & 15, half = lane >> 4;
  f32x4 acc[6] = {};
  for (int k0 = 0; k0 < D_MODEL; k0 += 64) {
    __syncthreads();
    // stage A: 64 rows x 64 k, fp32 -> bf16 in-flight; 4 float4 per thread
    #pragma unroll
    for (int i = 0; i < 4; ++i) {
      int cc = tid + i * 256;
      int r = cc >> 4, ko = (cc & 15) * 4;
      float4 v = *(const float4*)&X[(size_t)(row0 + r) * D_MODEL + k0 + ko];
      ushort4 o; o.x = f2bf(v.x); o.y = f2bf(v.y); o.z = f2bf(v.z); o.w = f2bf(v.w);
      *(ushort4*)&As[r * 64 + swz64(r, ko)] = o;
    }
    // stage B: 96 rows x 64 k bf16; 3 uint4 per thread
    #pragma unroll
    for (int i = 0; i < 3; ++i) {
      int cc = tid + i * 256;
      int r = cc >> 3, ko = (cc & 7) * 8;
      *(uint4*)&Bs[r * 64 + swz64(r, ko)] = *(const uint4*)&WT[(size_t)r * D_MODEL + k0 + ko];
    }
    __syncthreads();
    #pragma unroll
    for (int kk = 0; kk < 2; ++kk) {
      bf16x8 a = *(const bf16x8*)&As[(wave * 16 + lr) * 64 + swz64(lr, kk * 32 + half * 8)];
      #pragma unroll
      for (int n = 0; n < 6; ++n) {
        bf16x8 b = *(const bf16x8*)&Bs[(n * 16 + lr) * 64 + swz64(lr, kk * 32 + half * 8)];
        acc[n] = __builtin_amdgcn_mfma_f32_16x16x32_bf16(a, b, acc[n], 0, 0, 0);
      }
    }
  }
  #pragma unroll
  for (int n = 0; n < 6; ++n) {
    int gc = n * 16 + lr;
    #pragma unroll
    for (int r = 0; r < 4; ++r) {
      int gr = row0 + wave * 16 + half * 4 + r;
      Y[(size_t)gr * NDBL + gc] = acc[n][r];
    }
  }
}

// ---------------- 6. GEMM3 (MFMA): delta = softplus(dt @ Wdt + bdt) ----------------
// A = x_dbl[:, :64] (fp32->bf16 staged), B = WdtT [1024][64] bf16. Tile 128x128, BK=64=K.
__global__ __launch_bounds__(256) void gemm3(const float* __restrict__ XD,
                                             const unsigned short* __restrict__ WT, // [1024][64] bf16
                                             const float* __restrict__ bdt,
                                             float* __restrict__ Dl) {
  __shared__ __align__(16) unsigned short As[128 * 64];  // [m][k] swizzled
  __shared__ __align__(16) unsigned short Bs[128 * 64];  // [n][k] swizzled
  int tid = threadIdx.x;
  int row0 = blockIdx.x * 128;
  int col0 = blockIdx.y * 128;
  int wave = tid >> 6, lane = tid & 63;
  int wr = wave >> 1, wc = wave & 1;
  int lr = lane & 15, half = lane >> 4;
  // stage A: 128 rows x 64 fp32 -> bf16; 8 float4 per thread
  #pragma unroll
  for (int i = 0; i < 8; ++i) {
    int cc = tid + i * 256;
    int r = cc >> 4, ko = (cc & 15) * 4;
    float4 v = *(const float4*)&XD[(size_t)(row0 + r) * NDBL + ko];
    ushort4 o; o.x = f2bf(v.x); o.y = f2bf(v.y); o.z = f2bf(v.z); o.w = f2bf(v.w);
    *(ushort4*)&As[r * 64 + swz64(r, ko)] = o;
  }
  // stage B: 128 rows x 64 bf16; 4 uint4 per thread
  #pragma unroll
  for (int i = 0; i < 4; ++i) {
    int cc = tid + i * 256;
    int r = cc >> 3, ko = (cc & 7) * 8;
    *(uint4*)&Bs[r * 64 + swz64(r, ko)] = *(const uint4*)&WT[(size_t)(col0 + r) * DTRANK + ko];
  }
  __syncthreads();
  f32x4 acc[4][4] = {};
  #pragma unroll
  for (int kk = 0; kk < 2; ++kk) {
    bf16x8 a[4], b[4];
    #pragma unroll
    for (int m = 0; m < 4; ++m)
      a[m] = *(const bf16x8*)&As[(wr * 64 + m * 16 + lr) * 64 + swz64(lr, kk * 32 + half * 8)];
    #pragma unroll
    for (int n = 0; n < 4; ++n)
      b[n] = *(const bf16x8*)&Bs[(wc * 64 + n * 16 + lr) * 64 + swz64(lr, kk * 32 + half * 8)];
    #pragma unroll
    for (int m = 0; m < 4; ++m)
      #pragma unroll
      for (int n = 0; n < 4; ++n)
        acc[m][n] = __builtin_amdgcn_mfma_f32_16x16x32_bf16(a[m], b[n], acc[m][n], 0, 0, 0);
  }
  #pragma unroll
  for (int m = 0; m < 4; ++m) {
    int grb = row0 + wr * 64 + m * 16 + half * 4;
    #pragma unroll
    for (int n = 0; n < 4; ++n) {
      int gc = col0 + wc * 64 + n * 16 + lr;
      float bv = bdt[gc];
      #pragma unroll
      for (int r = 0; r < 4; ++r) {
        float z = acc[m][n][r] + bv;
        float sp = (z > 20.f) ? z : log1pf(__expf(z));
        Dl[(size_t)(grb + r) * D_MODEL + gc] = sp;
      }
    }
  }
}

// ---------------- 7-9. chunked linear-recurrence scan ----------------
__global__ __launch_bounds__(256) void scan_a(const float* __restrict__ delta,
                                              const float* __restrict__ x,
                                              const float* __restrict__ xdbl,
                                              const float* __restrict__ A_log,
                                              float* __restrict__ Pbuf,
                                              float* __restrict__ Hend) {
  int c = blockIdx.x, b = blockIdx.y, dq = blockIdx.z;
  int tid = threadIdx.x;
  int d = dq * 256 + tid;
  __shared__ __align__(16) float Bl[CLEN * 16];
  int rowbase = b * SEQ_L + c * CLEN;
  #pragma unroll
  for (int i = 0; i < 2; ++i) {
    int cc = tid + i * 256; int t = cc >> 2, no = (cc & 3) * 4;
    *(float4*)&Bl[t * 16 + no] = *(const float4*)&xdbl[(size_t)(rowbase + t) * NDBL + DTRANK + no];
  }
  __syncthreads();
  float Ar[16], h[16], P[16];
  #pragma unroll
  for (int n = 0; n < 16; ++n) { Ar[n] = -__expf(A_log[d * 16 + n]); h[n] = 0.f; P[n] = 1.f; }
  for (int t = 0; t < CLEN; ++t) {
    size_t roff = (size_t)(rowbase + t) * D_MODEL + d;
    float dlt = delta[roff];
    float xv = x[roff];
    float dx = dlt * xv;
    #pragma unroll
    for (int n = 0; n < 16; ++n) {
      float a = dlt * Ar[n];
      P[n] *= a;
      h[n] = a * h[n] + dx * Bl[t * 16 + n];
    }
  }
  size_t base = (size_t)c * (BATCH * D_MODEL * 16) + ((size_t)(b * D_MODEL + d)) * 16;
  #pragma unroll
  for (int n = 0; n < 16; n += 4) {
    *(float4*)&Pbuf[base + n] = make_float4(P[n], P[n+1], P[n+2], P[n+3]);
    *(float4*)&Hend[base + n] = make_float4(h[n], h[n+1], h[n+2], h[n+3]);
  }
}

__global__ __launch_bounds__(256) void scan_b(const float* __restrict__ P,
                                              const float* __restrict__ Hend,
                                              float* __restrict__ Hin) {
  int j = blockIdx.x * 256 + threadIdx.x;   // 65536 = B*D*16
  float H = 0.f;
  for (int c = 0; c < NCHUNK; ++c) {
    size_t off = (size_t)c * (BATCH * D_MODEL * 16) + j;
    Hin[off] = H;
    H = P[off] * H + Hend[off];
  }
}

__global__ __launch_bounds__(256) void scan_c(const float* __restrict__ delta,
                                              const float* __restrict__ x,
                                              const float* __restrict__ xdbl,
                                              const float* __restrict__ A_log,
                                              const float* __restrict__ Hin,
                                              const float* __restrict__ Dp,
                                              float* __restrict__ out) {
  int c = blockIdx.x, b = blockIdx.y, dq = blockIdx.z;
  int tid = threadIdx.x;
  int d = dq * 256 + tid;
  __shared__ __align__(16) float Bl[CLEN * 16];
  __shared__ __align__(16) float Cl[CLEN * 16];
  int rowbase = b * SEQ_L + c * CLEN;
  #pragma unroll
  for (int i = 0; i < 2; ++i) {
    int cc = tid + i * 256; int t = cc >> 2, no = (cc & 3) * 4;
    *(float4*)&Bl[t * 16 + no] = *(const float4*)&xdbl[(size_t)(rowbase + t) * NDBL + DTRANK + no];
    *(float4*)&Cl[t * 16 + no] = *(const float4*)&xdbl[(size_t)(rowbase + t) * NDBL + DTRANK + DSTATE + no];
  }
  __syncthreads();
  float Ar[16], h[16];
  size_t hbase = (size_t)c * (BATCH * D_MODEL * 16) + ((size_t)(b * D_MODEL + d)) * 16;
  #pragma unroll
  for (int n = 0; n < 16; n += 4) {
    float4 hv = *(const float4*)&Hin[hbase + n];
    h[n] = hv.x; h[n+1] = hv.y; h[n+2] = hv.z; h[n+3] = hv.w;
  }
  #pragma unroll
  for (int n = 0; n < 16; ++n) Ar[n] = -__expf(A_log[d * 16 + n]);
  float dpv = Dp[d];
  for (int t = 0; t < CLEN; ++t) {
    size_t roff = (size_t)(rowbase + t) * D_MODEL + d;
    float dlt = delta[roff];
    float xv = x[roff];
    float dx = dlt * xv;
    float y = 0.f;
    #pragma unroll
    for (int n = 0; n < 16; ++n) {
      float a = dlt * Ar[n];
      h[n] = a * h[n] + dx * Bl[t * 16 + n];
      y += h[n] * Cl[t * 16 + n];
    }
    out[roff] = y + xv * dpv;
  }
}

// ---------------- launch ----------------
extern "C" void kernel_launch(void* const* d_in, const int* in_sizes, int n_in,
                              void* d_out, int out_size, void* d_ws, size_t ws_size,
                              hipStream_t stream) {
  const float* f     = (const float*)d_in[0];
  const float* ln_g  = (const float*)d_in[1];
  const float* ln_b  = (const float*)d_in[2];
  const float* Wx    = (const float*)d_in[3];
  const float* bx    = (const float*)d_in[4];
  const float* convw = (const float*)d_in[5];
  const float* convb = (const float*)d_in[6];
  const float* Wxp   = (const float*)d_in[7];
  const float* Wdt   = (const float*)d_in[8];
  const float* bdt   = (const float*)d_in[9];
  const float* A_log = (const float*)d_in[10];
  const float* Dp    = (const float*)d_in[11];
  float* out = (float*)d_out;
  char* ws = (char*)d_ws;

  // layout (high-water 176.5 MiB):
  unsigned short* fnb = (unsigned short*)(ws);                 // 32 MiB, dead after gemm1
  float* xlin  = (float*)(ws + 33554432);                      // 64 MiB (aliased as delta later)
  float* xbuf  = (float*)(ws + 100663296);                     // 64 MiB conv+silu output
  float* xdbl  = (float*)(ws + 167772160);                     // 6 MiB
  unsigned short* wxt  = (unsigned short*)(ws + 174063616);    // 2 MiB Wx^T bf16
  unsigned short* wxpT = (unsigned short*)(ws + 176160768);    // 192 KiB Wxp^T bf16 [96][1024]
  unsigned short* wdtT = (unsigned short*)(ws + 176357376);    // 128 KiB Wdt^T bf16 [1024][64]
  float* delta = xlin;                                         // xlin dead after conv
  float* Pbuf  = (float*)(ws);                                 // alias fnb (dead after gemm1)
  float* Hend  = (float*)(ws + 8388608);
  float* Hin   = (float*)(ws + 16777216);

  tcast<<<dim3(32, 32), dim3(256), 0, stream>>>(Wx, wxt, 1024, 1024);
  tcast<<<dim3(3, 32),  dim3(256), 0, stream>>>(Wxp, wxpT, 1024, 96);
  tcast<<<dim3(32, 2),  dim3(256), 0, stream>>>(Wdt, wdtT, 64, 1024);
  ln_kernel<<<dim3(NROWS), dim3(256), 0, stream>>>(f, ln_g, ln_b, fnb);
  gemm1<<<dim3(NROWS / 128, D_MODEL / 128), dim3(256), 0, stream>>>(fnb, wxt, bx, xlin);
  conv_silu<<<dim3(NROWS * (D_MODEL / 4) / 256), dim3(256), 0, stream>>>(xlin, convw, convb, xbuf);
  gemm2<<<dim3(NROWS / 64), dim3(256), 0, stream>>>(xbuf, wxpT, xdbl);
  gemm3<<<dim3(NROWS / 128, D_MODEL / 128), dim3(256), 0, stream>>>(xdbl, wdtT, bdt, delta);
  scan_a<<<dim3(NCHUNK, BATCH, 4), dim3(256), 0, stream>>>(delta, xbuf, xdbl, A_log, Pbuf, Hend);
  scan_b<<<dim3(256), dim3(256), 0, stream>>>(Pbuf, Hend, Hin);
  scan_c<<<dim3(NCHUNK, BATCH, 4), dim3(256), 0, stream>>>(delta, xbuf, xdbl, A_log, Hin, Dp, out);
}

// Round 3
// 385.744 us; speedup vs baseline: 1.1175x; 1.0154x over previous
//
#include <hip/hip_runtime.h>
#include <cstdint>
#include <cstddef>

// ---------------- problem constants ----------------
#define D_MODEL 1024
#define SEQ_L   4096
#define BATCH   4
#define NROWS   (BATCH*SEQ_L)     // 16384
#define DSTATE  16
#define DTRANK  64
#define NDBL    96                // DTRANK + 2*DSTATE
#define NCHUNK  32                // scan chunks
#define CLEN    128               // L / NCHUNK

typedef __attribute__((ext_vector_type(8))) short bf16x8;
typedef __attribute__((ext_vector_type(4))) float f32x4;

typedef __attribute__((address_space(1))) const unsigned int* as1_u32p;
typedef __attribute__((address_space(3))) unsigned int* as3_u32p;

__device__ __forceinline__ void gload16(const void* g, void* l) {
  // async global->LDS, 16B per lane; LDS dest must be wave-uniform base + lane*16
  __builtin_amdgcn_global_load_lds((as1_u32p)g, (as3_u32p)l, 16, 0, 0);
}

__device__ __forceinline__ unsigned short f2bf(float f) {
  union { float f; unsigned u; } v; v.f = f;
  unsigned u = v.u;
  unsigned r = u + 0x7FFFu + ((u >> 16) & 1u);   // RNE
  return (unsigned short)(r >> 16);
}

__device__ __forceinline__ float silu(float v) {
  return v / (1.f + __expf(-v));
}

// XOR swizzle for 64-elem bf16 rows (128B): spreads the 16-lane column read
// across 8 bank groups -> 2-way (free, m136). Mask multiples of 8 keep
// 4/8-elem chunks contiguous.
__device__ __forceinline__ int swz64(int r, int e) { return e ^ ((r & 7) << 3); }

// ---------------- 1. LayerNorm -> bf16 ----------------
__global__ __launch_bounds__(256) void ln_kernel(const float* __restrict__ f,
                                                 const float* __restrict__ g,
                                                 const float* __restrict__ bta,
                                                 unsigned short* __restrict__ fnb) {
  int row = blockIdx.x;
  int tid = threadIdx.x;
  const float* fr = f + (size_t)row * D_MODEL;
  float4 v = *(const float4*)&fr[tid * 4];
  float s  = v.x + v.y + v.z + v.w;
  float ss = v.x*v.x + v.y*v.y + v.z*v.z + v.w*v.w;
  #pragma unroll
  for (int o = 32; o > 0; o >>= 1) { s += __shfl_down(s, o); ss += __shfl_down(ss, o); }
  __shared__ float rs[8];
  int lane = tid & 63, w = tid >> 6;
  if (lane == 0) { rs[w] = s; rs[4 + w] = ss; }
  __syncthreads();
  if (tid == 0) {
    float S = rs[0] + rs[1] + rs[2] + rs[3];
    float SS = rs[4] + rs[5] + rs[6] + rs[7];
    float mu = S * (1.f / D_MODEL);
    float var = SS * (1.f / D_MODEL) - mu * mu;
    rs[0] = mu; rs[1] = rsqrtf(var + 1e-5f);
  }
  __syncthreads();
  float mu = rs[0], rstd = rs[1];
  float4 gv = *(const float4*)&g[tid * 4];
  float4 bv = *(const float4*)&bta[tid * 4];
  ushort4 o;
  o.x = f2bf((v.x - mu) * rstd * gv.x + bv.x);
  o.y = f2bf((v.y - mu) * rstd * gv.y + bv.y);
  o.z = f2bf((v.z - mu) * rstd * gv.z + bv.z);
  o.w = f2bf((v.w - mu) * rstd * gv.w + bv.w);
  *(ushort4*)&fnb[(size_t)row * D_MODEL + tid * 4] = o;
}

// ---------------- 2. generic transpose+cast: src [rows][cols] f32 -> dst [cols][rows] bf16
__global__ __launch_bounds__(256) void tcast(const float* __restrict__ W,
                                             unsigned short* __restrict__ Wt,
                                             int rows, int cols) {
  __shared__ float tile[32][33];
  int tx = threadIdx.x & 31, ty = threadIdx.x >> 5;  // ty 0..7
  int c0 = blockIdx.x * 32, r0 = blockIdx.y * 32;
  #pragma unroll
  for (int i = 0; i < 4; ++i) {
    int r = ty + i * 8;
    tile[r][tx] = W[(size_t)(r0 + r) * cols + c0 + tx];
  }
  __syncthreads();
  #pragma unroll
  for (int i = 0; i < 4; ++i) {
    int n = ty + i * 8;
    Wt[(size_t)(c0 + n) * rows + r0 + tx] = f2bf(tile[tx][n]);
  }
}

// ---------------- 3. GEMM1: x_lin = fn @ Wx + bx  (bf16 MFMA, gload_lds staging) ----------------
// 128x128 tile, BK=32, 4 waves, each wave 64x64 (4x4 fragments of 16x16x32)
__global__ __launch_bounds__(256) void gemm1(const unsigned short* __restrict__ Ab,
                                             const unsigned short* __restrict__ Bt,
                                             const float* __restrict__ bias,
                                             float* __restrict__ C) {
  __shared__ __align__(16) unsigned short As[128 * 32];  // [m][k], linear (gload_lds)
  __shared__ __align__(16) unsigned short Bs[128 * 32];  // [n][k]
  const int K = D_MODEL, N = D_MODEL;
  int tid = threadIdx.x;
  int row0 = blockIdx.x * 128;
  int col0 = blockIdx.y * 128;
  int wave = tid >> 6, lane = tid & 63;
  int wr = wave >> 1, wc = wave & 1;
  int lr = lane & 15, half = lane >> 4;
  f32x4 acc[4][4] = {};
  // chunk c (16B): LDS elem offset = (c>>2)*32 + (c&3)*8 = c*8  -> linear, gload_lds-compatible
  int c0 = tid, c1 = tid + 256;
  int ar0 = c0 >> 2, ak0 = (c0 & 3) * 8;
  int ar1 = c1 >> 2, ak1 = (c1 & 3) * 8;
  for (int k0 = 0; k0 < K; k0 += 32) {
    __syncthreads();
    gload16(&Ab[(size_t)(row0 + ar0) * K + k0 + ak0], &As[c0 * 8]);
    gload16(&Ab[(size_t)(row0 + ar1) * K + k0 + ak1], &As[c1 * 8]);
    gload16(&Bt[(size_t)(col0 + ar0) * K + k0 + ak0], &Bs[c0 * 8]);
    gload16(&Bt[(size_t)(col0 + ar1) * K + k0 + ak1], &Bs[c1 * 8]);
    __syncthreads();
    bf16x8 a[4], b[4];
    #pragma unroll
    for (int m = 0; m < 4; ++m) a[m] = *(const bf16x8*)&As[(wr * 64 + m * 16 + lr) * 32 + half * 8];
    #pragma unroll
    for (int n = 0; n < 4; ++n) b[n] = *(const bf16x8*)&Bs[(wc * 64 + n * 16 + lr) * 32 + half * 8];
    #pragma unroll
    for (int m = 0; m < 4; ++m)
      #pragma unroll
      for (int n = 0; n < 4; ++n)
        acc[m][n] = __builtin_amdgcn_mfma_f32_16x16x32_bf16(a[m], b[n], acc[m][n], 0, 0, 0);
  }
  // C/D layout: col = lane&15, row = (lane>>4)*4 + reg
  #pragma unroll
  for (int m = 0; m < 4; ++m) {
    int grb = row0 + wr * 64 + m * 16 + half * 4;
    #pragma unroll
    for (int n = 0; n < 4; ++n) {
      int gc = col0 + wc * 64 + n * 16 + lr;
      float bv = bias[gc];
      #pragma unroll
      for (int r = 0; r < 4; ++r)
        C[(size_t)(grb + r) * N + gc] = acc[m][n][r] + bv;
    }
  }
}

// ---------------- 4. causal depthwise conv (K=4) + bias + SiLU ----------------
__global__ __launch_bounds__(256) void conv_silu(const float* __restrict__ xlin,
                                                 const float* __restrict__ cw,
                                                 const float* __restrict__ cb,
                                                 float* __restrict__ xo) {
  int idx = blockIdx.x * 256 + threadIdx.x;   // one float4 along D
  int d4 = idx & 255;
  int rowflat = idx >> 8;                     // b*L + l
  int l = rowflat & (SEQ_L - 1);
  int d = d4 * 4;
  float4 cbv = *(const float4*)&cb[d];
  float a0 = cbv.x, a1 = cbv.y, a2 = cbv.z, a3 = cbv.w;
  float w[4][4];
  #pragma unroll
  for (int j = 0; j < 4; ++j) {
    float4 t = *(const float4*)&cw[(d + j) * 4];
    w[j][0] = t.x; w[j][1] = t.y; w[j][2] = t.z; w[j][3] = t.w;
  }
  #pragma unroll
  for (int k = 0; k < 4; ++k) {
    int ls = l - 3 + k;
    if (ls >= 0) {
      float4 v = *(const float4*)&xlin[(size_t)(rowflat - 3 + k) * D_MODEL + d];
      a0 += v.x * w[0][k]; a1 += v.y * w[1][k]; a2 += v.z * w[2][k]; a3 += v.w * w[3][k];
    }
  }
  float4 o; o.x = silu(a0); o.y = silu(a1); o.z = silu(a2); o.w = silu(a3);
  *(float4*)&xo[(size_t)rowflat * D_MODEL + d] = o;
}

// ---------------- 5. GEMM2 (MFMA): x_dbl = x @ Wxp  (16384x1024 @ 1024x96) ----------------
// tile M=64, N=96 (full), BK=64; 4 waves, wave w: rows w*16..w*16+15, 6 n-frags
__global__ __launch_bounds__(256) void gemm2(const float* __restrict__ X,
                                             const unsigned short* __restrict__ WT, // [96][1024] bf16
                                             float* __restrict__ Y) {
  __shared__ __align__(16) unsigned short As[64 * 64];   // [m][k] swizzled
  __shared__ __align__(16) unsigned short Bs[96 * 64];   // [n][k] swizzled
  int tid = threadIdx.x;
  int row0 = blockIdx.x * 64;
  int wave = tid >> 6, lane = tid & 63;
  int lr = lane & 15, half = lane >> 4;
  f32x4 acc[6] = {};
  for (int k0 = 0; k0 < D_MODEL; k0 += 64) {
    __syncthreads();
    // stage A: 64 rows x 64 k, fp32 -> bf16 in-flight; 4 float4 per thread
    #pragma unroll
    for (int i = 0; i < 4; ++i) {
      int cc = tid + i * 256;
      int r = cc >> 4, ko = (cc & 15) * 4;
      float4 v = *(const float4*)&X[(size_t)(row0 + r) * D_MODEL + k0 + ko];
      ushort4 o; o.x = f2bf(v.x); o.y = f2bf(v.y); o.z = f2bf(v.z); o.w = f2bf(v.w);
      *(ushort4*)&As[r * 64 + swz64(r, ko)] = o;
    }
    // stage B: 96 rows x 64 k bf16; 3 uint4 per thread
    #pragma unroll
    for (int i = 0; i < 3; ++i) {
      int cc = tid + i * 256;
      int r = cc >> 3, ko = (cc & 7) * 8;
      *(uint4*)&Bs[r * 64 + swz64(r, ko)] = *(const uint4*)&WT[(size_t)r * D_MODEL + k0 + ko];
    }
    __syncthreads();
    #pragma unroll
    for (int kk = 0; kk < 2; ++kk) {
      bf16x8 a = *(const bf16x8*)&As[(wave * 16 + lr) * 64 + swz64(lr, kk * 32 + half * 8)];
      #pragma unroll
      for (int n = 0; n < 6; ++n) {
        bf16x8 b = *(const bf16x8*)&Bs[(n * 16 + lr) * 64 + swz64(lr, kk * 32 + half * 8)];
        acc[n] = __builtin_amdgcn_mfma_f32_16x16x32_bf16(a, b, acc[n], 0, 0, 0);
      }
    }
  }
  #pragma unroll
  for (int n = 0; n < 6; ++n) {
    int gc = n * 16 + lr;
    #pragma unroll
    for (int r = 0; r < 4; ++r) {
      int gr = row0 + wave * 16 + half * 4 + r;
      Y[(size_t)gr * NDBL + gc] = acc[n][r];
    }
  }
}

// ---------------- 6. GEMM3 (MFMA): delta = softplus(dt @ Wdt + bdt) ----------------
// A = x_dbl[:, :64] (fp32->bf16 staged), B = WdtT [1024][64] bf16. Tile 128x128, BK=64=K.
__global__ __launch_bounds__(256) void gemm3(const float* __restrict__ XD,
                                             const unsigned short* __restrict__ WT, // [1024][64] bf16
                                             const float* __restrict__ bdt,
                                             float* __restrict__ Dl) {
  __shared__ __align__(16) unsigned short As[128 * 64];  // [m][k] swizzled
  __shared__ __align__(16) unsigned short Bs[128 * 64];  // [n][k] swizzled
  int tid = threadIdx.x;
  int row0 = blockIdx.x * 128;
  int col0 = blockIdx.y * 128;
  int wave = tid >> 6, lane = tid & 63;
  int wr = wave >> 1, wc = wave & 1;
  int lr = lane & 15, half = lane >> 4;
  // stage A: 128 rows x 64 fp32 -> bf16; 8 float4 per thread
  #pragma unroll
  for (int i = 0; i < 8; ++i) {
    int cc = tid + i * 256;
    int r = cc >> 4, ko = (cc & 15) * 4;
    float4 v = *(const float4*)&XD[(size_t)(row0 + r) * NDBL + ko];
    ushort4 o; o.x = f2bf(v.x); o.y = f2bf(v.y); o.z = f2bf(v.z); o.w = f2bf(v.w);
    *(ushort4*)&As[r * 64 + swz64(r, ko)] = o;
  }
  // stage B: 128 rows x 64 bf16; 4 uint4 per thread
  #pragma unroll
  for (int i = 0; i < 4; ++i) {
    int cc = tid + i * 256;
    int r = cc >> 3, ko = (cc & 7) * 8;
    *(uint4*)&Bs[r * 64 + swz64(r, ko)] = *(const uint4*)&WT[(size_t)(col0 + r) * DTRANK + ko];
  }
  __syncthreads();
  f32x4 acc[4][4] = {};
  #pragma unroll
  for (int kk = 0; kk < 2; ++kk) {
    bf16x8 a[4], b[4];
    #pragma unroll
    for (int m = 0; m < 4; ++m)
      a[m] = *(const bf16x8*)&As[(wr * 64 + m * 16 + lr) * 64 + swz64(lr, kk * 32 + half * 8)];
    #pragma unroll
    for (int n = 0; n < 4; ++n)
      b[n] = *(const bf16x8*)&Bs[(wc * 64 + n * 16 + lr) * 64 + swz64(lr, kk * 32 + half * 8)];
    #pragma unroll
    for (int m = 0; m < 4; ++m)
      #pragma unroll
      for (int n = 0; n < 4; ++n)
        acc[m][n] = __builtin_amdgcn_mfma_f32_16x16x32_bf16(a[m], b[n], acc[m][n], 0, 0, 0);
  }
  #pragma unroll
  for (int m = 0; m < 4; ++m) {
    int grb = row0 + wr * 64 + m * 16 + half * 4;
    #pragma unroll
    for (int n = 0; n < 4; ++n) {
      int gc = col0 + wc * 64 + n * 16 + lr;
      float bv = bdt[gc];
      #pragma unroll
      for (int r = 0; r < 4; ++r) {
        float z = acc[m][n][r] + bv;
        float sp = (z > 20.f) ? z : log1pf(__expf(z));
        Dl[(size_t)(grb + r) * D_MODEL + gc] = sp;
      }
    }
  }
}

// ---------------- 7-9. chunked linear-recurrence scan ----------------
__global__ __launch_bounds__(256) void scan_a(const float* __restrict__ delta,
                                              const float* __restrict__ x,
                                              const float* __restrict__ xdbl,
                                              const float* __restrict__ A_log,
                                              float* __restrict__ Pbuf,
                                              float* __restrict__ Hend) {
  int c = blockIdx.x, b = blockIdx.y, dq = blockIdx.z;
  int tid = threadIdx.x;
  int d = dq * 256 + tid;
  __shared__ __align__(16) float Bl[CLEN * 16];
  int rowbase = b * SEQ_L + c * CLEN;
  #pragma unroll
  for (int i = 0; i < 2; ++i) {
    int cc = tid + i * 256; int t = cc >> 2, no = (cc & 3) * 4;
    *(float4*)&Bl[t * 16 + no] = *(const float4*)&xdbl[(size_t)(rowbase + t) * NDBL + DTRANK + no];
  }
  __syncthreads();
  float Ar[16], h[16], P[16];
  #pragma unroll
  for (int n = 0; n < 16; ++n) { Ar[n] = -__expf(A_log[d * 16 + n]); h[n] = 0.f; P[n] = 1.f; }
  for (int t = 0; t < CLEN; ++t) {
    size_t roff = (size_t)(rowbase + t) * D_MODEL + d;
    float dlt = delta[roff];
    float xv = x[roff];
    float dx = dlt * xv;
    #pragma unroll
    for (int n = 0; n < 16; ++n) {
      float a = dlt * Ar[n];
      P[n] *= a;
      h[n] = a * h[n] + dx * Bl[t * 16 + n];
    }
  }
  size_t base = (size_t)c * (BATCH * D_MODEL * 16) + ((size_t)(b * D_MODEL + d)) * 16;
  #pragma unroll
  for (int n = 0; n < 16; n += 4) {
    *(float4*)&Pbuf[base + n] = make_float4(P[n], P[n+1], P[n+2], P[n+3]);
    *(float4*)&Hend[base + n] = make_float4(h[n], h[n+1], h[n+2], h[n+3]);
  }
}

__global__ __launch_bounds__(256) void scan_b(const float* __restrict__ P,
                                              const float* __restrict__ Hend,
                                              float* __restrict__ Hin) {
  int j = blockIdx.x * 256 + threadIdx.x;   // 65536 = B*D*16
  float H = 0.f;
  for (int c = 0; c < NCHUNK; ++c) {
    size_t off = (size_t)c * (BATCH * D_MODEL * 16) + j;
    Hin[off] = H;
    H = P[off] * H + Hend[off];
  }
}

__global__ __launch_bounds__(256) void scan_c(const float* __restrict__ delta,
                                              const float* __restrict__ x,
                                              const float* __restrict__ xdbl,
                                              const float* __restrict__ A_log,
                                              const float* __restrict__ Hin,
                                              const float* __restrict__ Dp,
                                              float* __restrict__ out) {
  int c = blockIdx.x, b = blockIdx.y, dq = blockIdx.z;
  int tid = threadIdx.x;
  int d = dq * 256 + tid;
  __shared__ __align__(16) float Bl[CLEN * 16];
  __shared__ __align__(16) float Cl[CLEN * 16];
  int rowbase = b * SEQ_L + c * CLEN;
  #pragma unroll
  for (int i = 0; i < 2; ++i) {
    int cc = tid + i * 256; int t = cc >> 2, no = (cc & 3) * 4;
    *(float4*)&Bl[t * 16 + no] = *(const float4*)&xdbl[(size_t)(rowbase + t) * NDBL + DTRANK + no];
    *(float4*)&Cl[t * 16 + no] = *(const float4*)&xdbl[(size_t)(rowbase + t) * NDBL + DTRANK + DSTATE + no];
  }
  __syncthreads();
  float Ar[16], h[16];
  size_t hbase = (size_t)c * (BATCH * D_MODEL * 16) + ((size_t)(b * D_MODEL + d)) * 16;
  #pragma unroll
  for (int n = 0; n < 16; n += 4) {
    float4 hv = *(const float4*)&Hin[hbase + n];
    h[n] = hv.x; h[n+1] = hv.y; h[n+2] = hv.z; h[n+3] = hv.w;
  }
  #pragma unroll
  for (int n = 0; n < 16; ++n) Ar[n] = -__expf(A_log[d * 16 + n]);
  float dpv = Dp[d];
  for (int t = 0; t < CLEN; ++t) {
    size_t roff = (size_t)(rowbase + t) * D_MODEL + d;
    float dlt = delta[roff];
    float xv = x[roff];
    float dx = dlt * xv;
    float y = 0.f;
    #pragma unroll
    for (int n = 0; n < 16; ++n) {
      float a = dlt * Ar[n];
      h[n] = a * h[n] + dx * Bl[t * 16 + n];
      y += h[n] * Cl[t * 16 + n];
    }
    out[roff] = y + xv * dpv;
  }
}

// ---------------- launch ----------------
extern "C" void kernel_launch(void* const* d_in, const int* in_sizes, int n_in,
                              void* d_out, int out_size, void* d_ws, size_t ws_size,
                              hipStream_t stream) {
  const float* f     = (const float*)d_in[0];
  const float* ln_g  = (const float*)d_in[1];
  const float* ln_b  = (const float*)d_in[2];
  const float* Wx    = (const float*)d_in[3];
  const float* bx    = (const float*)d_in[4];
  const float* convw = (const float*)d_in[5];
  const float* convb = (const float*)d_in[6];
  const float* Wxp   = (const float*)d_in[7];
  const float* Wdt   = (const float*)d_in[8];
  const float* bdt   = (const float*)d_in[9];
  const float* A_log = (const float*)d_in[10];
  const float* Dp    = (const float*)d_in[11];
  float* out = (float*)d_out;
  char* ws = (char*)d_ws;

  // layout (high-water 176.5 MiB):
  unsigned short* fnb = (unsigned short*)(ws);                 // 32 MiB, dead after gemm1
  float* xlin  = (float*)(ws + 33554432);                      // 64 MiB (aliased as delta later)
  float* xbuf  = (float*)(ws + 100663296);                     // 64 MiB conv+silu output
  float* xdbl  = (float*)(ws + 167772160);                     // 6 MiB
  unsigned short* wxt  = (unsigned short*)(ws + 174063616);    // 2 MiB Wx^T bf16
  unsigned short* wxpT = (unsigned short*)(ws + 176160768);    // 192 KiB Wxp^T bf16 [96][1024]
  unsigned short* wdtT = (unsigned short*)(ws + 176357376);    // 128 KiB Wdt^T bf16 [1024][64]
  float* delta = xlin;                                         // xlin dead after conv
  float* Pbuf  = (float*)(ws);                                 // alias fnb (dead after gemm1)
  float* Hend  = (float*)(ws + 8388608);
  float* Hin   = (float*)(ws + 16777216);

  tcast<<<dim3(32, 32), dim3(256), 0, stream>>>(Wx, wxt, 1024, 1024);
  tcast<<<dim3(3, 32),  dim3(256), 0, stream>>>(Wxp, wxpT, 1024, 96);
  tcast<<<dim3(32, 2),  dim3(256), 0, stream>>>(Wdt, wdtT, 64, 1024);
  ln_kernel<<<dim3(NROWS), dim3(256), 0, stream>>>(f, ln_g, ln_b, fnb);
  gemm1<<<dim3(NROWS / 128, D_MODEL / 128), dim3(256), 0, stream>>>(fnb, wxt, bx, xlin);
  conv_silu<<<dim3(NROWS * (D_MODEL / 4) / 256), dim3(256), 0, stream>>>(xlin, convw, convb, xbuf);
  gemm2<<<dim3(NROWS / 64), dim3(256), 0, stream>>>(xbuf, wxpT, xdbl);
  gemm3<<<dim3(NROWS / 128, D_MODEL / 128), dim3(256), 0, stream>>>(xdbl, wdtT, bdt, delta);
  scan_a<<<dim3(NCHUNK, BATCH, 4), dim3(256), 0, stream>>>(delta, xbuf, xdbl, A_log, Pbuf, Hend);
  scan_b<<<dim3(256), dim3(256), 0, stream>>>(Pbuf, Hend, Hin);
  scan_c<<<dim3(NCHUNK, BATCH, 4), dim3(256), 0, stream>>>(delta, xbuf, xdbl, A_log, Hin, Dp, out);
}